// Round 10
// baseline (396.583 us; speedup 1.0000x reference)
//
#include <hip/hip_runtime.h>

#define N_NODES    100000
#define N_EDGES    1600000
#define IN_F       64
#define OUT_F      40
#define N_CLUSTERS 10000

#define BUCK_SHIFT 7                                  // 128 rows per bucket
#define BROWS      128
#define NBUCK      ((N_NODES + BROWS - 1) >> BUCK_SHIFT)   // 782
#define CAP        2560                               // mean 2048, sigma 45 -> +11 sigma
#define TILE_E     4096
#define EPT        (TILE_E / 256)                     // 16 edges per thread

// ---------------------------------------------------------------- bin scatter (single edge pass)
__global__ __launch_bounds__(256) void bin_scatter_kernel(
        const int* __restrict__ rows, const int* __restrict__ cols,
        int* __restrict__ bcursor, unsigned* __restrict__ bins) {
    __shared__ uint2 se[TILE_E];          // 32 KB, ordered by bucket
    __shared__ int lh[NBUCK];
    __shared__ int lsc[NBUCK];
    __shared__ int lb[NBUCK];
    __shared__ int sc[256];
    int t = threadIdx.x;
    for (int i = t; i < NBUCK; i += 256) lh[i] = 0;
    __syncthreads();
    int e0 = blockIdx.x * TILE_E;
    int r[EPT], c[EPT], rk[EPT];
    #pragma unroll
    for (int k = 0; k < EPT; ++k) {
        int e = e0 + t + k * 256;
        if (e < N_EDGES) {
            r[k] = rows[e]; c[k] = cols[e];
            rk[k] = atomicAdd(&lh[r[k] >> BUCK_SHIFT], 1);
        } else r[k] = -1;
    }
    __syncthreads();
    int b4 = t * 4;
    int a0 = (b4 + 0 < NBUCK) ? lh[b4 + 0] : 0;
    int a1 = (b4 + 1 < NBUCK) ? lh[b4 + 1] : 0;
    int a2 = (b4 + 2 < NBUCK) ? lh[b4 + 2] : 0;
    int a3 = (b4 + 3 < NBUCK) ? lh[b4 + 3] : 0;
    int thr = a0 + a1 + a2 + a3;
    sc[t] = thr;
    __syncthreads();
    for (int off = 1; off < 256; off <<= 1) {
        int a = (t >= off) ? sc[t - off] : 0;
        __syncthreads();
        sc[t] += a;
        __syncthreads();
    }
    int ex = sc[t] - thr;
    if (b4 + 0 < NBUCK) { lsc[b4 + 0] = ex;                lb[b4 + 0] = a0 ? atomicAdd(&bcursor[b4 + 0], a0) : 0; }
    if (b4 + 1 < NBUCK) { lsc[b4 + 1] = ex + a0;           lb[b4 + 1] = a1 ? atomicAdd(&bcursor[b4 + 1], a1) : 0; }
    if (b4 + 2 < NBUCK) { lsc[b4 + 2] = ex + a0 + a1;      lb[b4 + 2] = a2 ? atomicAdd(&bcursor[b4 + 2], a2) : 0; }
    if (b4 + 3 < NBUCK) { lsc[b4 + 3] = ex + a0 + a1 + a2; lb[b4 + 3] = a3 ? atomicAdd(&bcursor[b4 + 3], a3) : 0; }
    __syncthreads();
    #pragma unroll
    for (int k = 0; k < EPT; ++k) {
        if (r[k] >= 0) {
            int bu = r[k] >> BUCK_SHIFT;
            se[lsc[bu] + rk[k]] = make_uint2((unsigned)r[k], (unsigned)c[k]);
        }
    }
    __syncthreads();
    #pragma unroll
    for (int k = 0; k < EPT; ++k) {
        int idx = k * 256 + t;
        if (e0 + idx < N_EDGES) {
            uint2 u = se[idx];
            int bu = (int)(u.x >> BUCK_SHIFT);
            int pos = lb[bu] + (idx - lsc[bu]);
            if (pos < CAP)
                bins[(size_t)bu * CAP + pos] = ((u.x & (BROWS - 1)) << 17) | u.y;
        }
    }
}

// ---------------------------------------------------------------- CSR build per bucket
__global__ __launch_bounds__(256) void csr_build_kernel(
        const unsigned* __restrict__ bins, const int* __restrict__ bcnt,
        int* __restrict__ csr_col, uint2* __restrict__ rowinfo,
        float* __restrict__ dinv, const int* __restrict__ cl,
        int* __restrict__ ccnt) {
    __shared__ int lcnt[BROWS];
    __shared__ int gbeg[BROWS];
    __shared__ int sc[BROWS];
    int b = blockIdx.x, t = threadIdx.x;
    int n = min(bcnt[b], CAP);
    const unsigned* eb = bins + (size_t)b * CAP;
    if (t < BROWS) lcnt[t] = 0;
    __syncthreads();
    for (int i = t; i < n; i += 256) atomicAdd(&lcnt[eb[i] >> 17], 1);
    __syncthreads();
    int v = (t < BROWS) ? lcnt[t] : 0;
    if (t < BROWS) sc[t] = v;
    __syncthreads();
    for (int off = 1; off < BROWS; off <<= 1) {
        int a = (t >= off && t < BROWS) ? sc[t - off] : 0;
        __syncthreads();
        if (t < BROWS) sc[t] += a;
        __syncthreads();
    }
    if (t < BROWS) {
        int beg = b * CAP + sc[t] - v;
        gbeg[t] = beg;
        int grow = (b << BUCK_SHIFT) + t;
        if (grow < N_NODES) {
            rowinfo[grow] = make_uint2((unsigned)beg, (unsigned)v);
            dinv[grow] = rsqrtf((float)(v + 1));
            atomicAdd(&ccnt[cl[grow]], 1);
        }
        lcnt[t] = 0;        // reuse as per-row cursor
    }
    __syncthreads();
    for (int i = t; i < n; i += 256) {
        unsigned u = eb[i];
        int lrow = (int)(u >> 17);
        int pos = atomicAdd(&lcnt[lrow], 1);
        csr_col[gbeg[lrow] + pos] = (int)(u & 0x1FFFFu);
    }
}

// ---------------------------------------------------------------- prologue: z0 = dinv * (x @ W^T)
__global__ __launch_bounds__(256, 8) void prologue_kernel(
        const float4* __restrict__ x4, const float* __restrict__ W,
        const float* __restrict__ dinv, float* __restrict__ z0) {
    __shared__ float Ws[OUT_F * 65];
    int t = threadIdx.x;
    for (int i = t; i < OUT_F * IN_F; i += 256)
        Ws[(i >> 6) * 65 + (i & 63)] = W[i];
    __syncthreads();
    int idx = blockIdx.x * 256 + t;
    if (idx >= N_NODES * OUT_F) return;
    int node = idx / OUT_F;
    int o = idx - node * OUT_F;
    const float4* xr = x4 + node * 16;
    const float* wr = Ws + o * 65;
    float acc = 0.f;
    #pragma unroll
    for (int k4 = 0; k4 < 16; ++k4) {
        float4 v = xr[k4];
        acc += v.x * wr[k4 * 4 + 0] + v.y * wr[k4 * 4 + 1]
             + v.z * wr[k4 * 4 + 2] + v.w * wr[k4 * 4 + 3];
    }
    z0[idx] = acc * dinv[node];
}

// ---------------------------------------------------------------- 40-dim pull hop, 16 nodes/block
// wave per node group (slot 0..5 x ql 0..9, float4/lane); rows staged in LDS and
// flushed as one contiguous 2560 B burst. FINAL: dinv-scaled atomicAdd into xc[cl].
// NOTE: the gather loop keeps a UNIFORM trip count across all 64 lanes —
// __shfl executes unconditionally (guard AFTER the shfl). A per-lane loop bound
// (R8/R9) makes shfl read exec-masked-off lanes => undefined values (absmax 3.7e-2).
template<int FINAL>
__global__ __launch_bounds__(256, 8) void hop40_kernel(
        const float4* __restrict__ in4, float4* __restrict__ out4,
        const uint2* __restrict__ rowinfo, const int* __restrict__ csr_col,
        const float* __restrict__ dinv, const int* __restrict__ cl,
        float* __restrict__ xc) {
    __shared__ float4 srow[160];          // 16 rows x 10 float4 = 2560 B
    int t = threadIdx.x;
    int w = t >> 6;
    int lane = t & 63;
    int slot = lane / 10;                 // 6 => lanes 60..63 idle (still shfl sources)
    int ql = lane - slot * 10;
    int slotj = (slot < 6) ? slot : 1000; // idle slots never pass the j<lim guard
    int nb = blockIdx.x << 4;
    #pragma unroll
    for (int i = 0; i < 4; ++i) {
        int node = nb + (w << 2) + i;
        uint2 ri = rowinfo[node];
        int beg = (int)ri.x;
        int end = beg + (int)ri.y;
        float4 acc = make_float4(0.f, 0.f, 0.f, 0.f);
        if (slot == 0) acc = in4[(size_t)node * 10 + ql];     // self-loop
        for (int base = beg; base < end; base += 64) {
            int idx = base + lane;
            int cv = (idx < end) ? csr_col[idx] : 0;
            int lim = min(64, end - base);
            #pragma unroll
            for (int r = 0; r < 11; ++r) {
                int j = r * 6 + slotj;                // uniform trip count, all lanes
                int c = __shfl(cv, j & 63);           // shfl BEFORE guard
                if (j < lim) {
                    float4 vv = in4[(size_t)c * 10 + ql];
                    acc.x += vv.x; acc.y += vv.y; acc.z += vv.z; acc.w += vv.w;
                }
            }
        }
        // reduce 6 slots: fold +30, then +10 and +20
        float4 t1;
        t1.x = __shfl(acc.x, (lane + 30) & 63); t1.y = __shfl(acc.y, (lane + 30) & 63);
        t1.z = __shfl(acc.z, (lane + 30) & 63); t1.w = __shfl(acc.w, (lane + 30) & 63);
        if (lane < 30) { acc.x += t1.x; acc.y += t1.y; acc.z += t1.z; acc.w += t1.w; }
        float4 t2, t3;
        t2.x = __shfl(acc.x, (lane + 10) & 63); t2.y = __shfl(acc.y, (lane + 10) & 63);
        t2.z = __shfl(acc.z, (lane + 10) & 63); t2.w = __shfl(acc.w, (lane + 10) & 63);
        t3.x = __shfl(acc.x, (lane + 20) & 63); t3.y = __shfl(acc.y, (lane + 20) & 63);
        t3.z = __shfl(acc.z, (lane + 20) & 63); t3.w = __shfl(acc.w, (lane + 20) & 63);
        if (lane < 10) {
            acc.x += t2.x + t3.x; acc.y += t2.y + t3.y;
            acc.z += t2.z + t3.z; acc.w += t2.w + t3.w;
            float d = dinv[node];
            if (FINAL) {
                float* p = xc + cl[node] * OUT_F + ql * 4;
                atomicAdd(p + 0, acc.x * d); atomicAdd(p + 1, acc.y * d);
                atomicAdd(p + 2, acc.z * d); atomicAdd(p + 3, acc.w * d);
            } else {
                float s = d * d;
                acc.x *= s; acc.y *= s; acc.z *= s; acc.w *= s;
                srow[((w << 2) + i) * 10 + ql] = acc;
            }
        }
    }
    if (!FINAL) {
        __syncthreads();
        if (t < 160) out4[(size_t)blockIdx.x * 160 + t] = srow[t];
    }
}

// ---------------------------------------------------------------- epilogue: out[n] = xc[cl[n]]/cnt + b
__global__ void epilogue_kernel(const float4* __restrict__ xc4, const int* __restrict__ ccnt,
                                const float4* __restrict__ b4, const int* __restrict__ cl,
                                float4* __restrict__ out4) {
    int i = blockIdx.x * 256 + threadIdx.x;
    if (i >= N_NODES * (OUT_F / 4)) return;
    int node = i / 10;
    int q = i - node * 10;
    int c = cl[node];
    float inv = 1.0f / fmaxf((float)ccnt[c], 1.0f);
    float4 v = xc4[c * 10 + q];
    float4 bb = b4[q];
    v.x = v.x * inv + bb.x; v.y = v.y * inv + bb.y;
    v.z = v.z * inv + bb.z; v.w = v.w * inv + bb.w;
    out4[i] = v;
}

// ---------------------------------------------------------------- launch
extern "C" void kernel_launch(void* const* d_in, const int* in_sizes, int n_in,
                              void* d_out, int out_size, void* d_ws, size_t ws_size,
                              hipStream_t stream) {
    const float* x    = (const float*)d_in[0];
    const int*   rows = (const int*)d_in[1];
    const int*   cols = (const int*)d_in[1] + N_EDGES;
    const int*   cl   = (const int*)d_in[2];
    const float* W    = (const float*)d_in[4];
    const float* b    = (const float*)d_in[5];
    float* out = (float*)d_out;

    size_t off = 0;
    auto alloc = [&](size_t elems) -> void* {          // 256 B aligned
        void* p = (char*)d_ws + off * 4;
        off += (elems + 63) & ~(size_t)63;
        return p;
    };
    // zeroed region first (single memset): ccnt | xc_sum | bcursor
    int*   ccnt    = (int*)alloc(N_CLUSTERS);
    float* xc_sum  = (float*)alloc((size_t)N_CLUSTERS * OUT_F);
    int*   bcursor = (int*)alloc(NBUCK);
    size_t zero_elems = off;
    float* dinv      = (float*)alloc(N_NODES);
    uint2* rowinfo   = (uint2*)alloc((size_t)N_NODES * 2);
    int*   csr_col   = (int*)alloc((size_t)NBUCK * CAP);            // 8 MB
    unsigned* bins   = (unsigned*)alloc((size_t)NBUCK * CAP);       // 8 MB
    float* bufA      = (float*)alloc((size_t)N_NODES * OUT_F);      // 16 MB
    float* bufB      = (float*)alloc((size_t)N_NODES * OUT_F);      // 16 MB
    (void)ws_size; (void)in_sizes; (void)n_in; (void)out_size;

    hipMemsetAsync(d_ws, 0, zero_elems * 4, stream);

    const int TB = (N_EDGES + TILE_E - 1) / TILE_E;   // 391
    const int HB = N_NODES / 16;                      // 6250

    bin_scatter_kernel<<<TB, 256, 0, stream>>>(rows, cols, bcursor, bins);
    csr_build_kernel<<<NBUCK, 256, 0, stream>>>(bins, bcursor, csr_col, rowinfo,
                                                dinv, cl, ccnt);

    prologue_kernel<<<(N_NODES * OUT_F + 255) / 256, 256, 0, stream>>>(
        (const float4*)x, W, dinv, bufA);

    hop40_kernel<0><<<HB, 256, 0, stream>>>((const float4*)bufA, (float4*)bufB,
                                            rowinfo, csr_col, dinv, cl, xc_sum);
    hop40_kernel<0><<<HB, 256, 0, stream>>>((const float4*)bufB, (float4*)bufA,
                                            rowinfo, csr_col, dinv, cl, xc_sum);
    hop40_kernel<1><<<HB, 256, 0, stream>>>((const float4*)bufA, (float4*)nullptr,
                                            rowinfo, csr_col, dinv, cl, xc_sum);

    epilogue_kernel<<<(N_NODES * (OUT_F / 4) + 255) / 256, 256, 0, stream>>>(
        (const float4*)xc_sum, ccnt, (const float4*)b, cl, (float4*)out);
}

// Round 12
// 366.192 us; speedup vs baseline: 1.0830x; 1.0830x over previous
//
#include <hip/hip_runtime.h>

#define N_NODES    100000
#define N_EDGES    1600000
#define IN_F       64
#define OUT_F      40
#define N_CLUSTERS 10000

#define BUCK_SHIFT 7                                  // 128 rows per bucket
#define BROWS      128
#define NBUCK      ((N_NODES + BROWS - 1) >> BUCK_SHIFT)   // 782
#define CAP        2560                               // mean 2048, sigma 45 -> +11 sigma
#define TILE_E     4096
#define EPT        (TILE_E / 256)                     // 16 edges per thread

typedef _Float16 half_t;
typedef _Float16 half4_t __attribute__((ext_vector_type(4)));

// ---------------------------------------------------------------- bin scatter (single edge pass)
__global__ __launch_bounds__(256) void bin_scatter_kernel(
        const int* __restrict__ rows, const int* __restrict__ cols,
        int* __restrict__ bcursor, unsigned* __restrict__ bins) {
    __shared__ uint2 se[TILE_E];          // 32 KB, ordered by bucket
    __shared__ int lh[NBUCK];
    __shared__ int lsc[NBUCK];
    __shared__ int lb[NBUCK];
    __shared__ int sc[256];
    int t = threadIdx.x;
    for (int i = t; i < NBUCK; i += 256) lh[i] = 0;
    __syncthreads();
    int e0 = blockIdx.x * TILE_E;
    int r[EPT], c[EPT], rk[EPT];
    #pragma unroll
    for (int k = 0; k < EPT; ++k) {
        int e = e0 + t + k * 256;
        if (e < N_EDGES) {
            r[k] = rows[e]; c[k] = cols[e];
            rk[k] = atomicAdd(&lh[r[k] >> BUCK_SHIFT], 1);
        } else r[k] = -1;
    }
    __syncthreads();
    int b4 = t * 4;
    int a0 = (b4 + 0 < NBUCK) ? lh[b4 + 0] : 0;
    int a1 = (b4 + 1 < NBUCK) ? lh[b4 + 1] : 0;
    int a2 = (b4 + 2 < NBUCK) ? lh[b4 + 2] : 0;
    int a3 = (b4 + 3 < NBUCK) ? lh[b4 + 3] : 0;
    int thr = a0 + a1 + a2 + a3;
    sc[t] = thr;
    __syncthreads();
    for (int off = 1; off < 256; off <<= 1) {
        int a = (t >= off) ? sc[t - off] : 0;
        __syncthreads();
        sc[t] += a;
        __syncthreads();
    }
    int ex = sc[t] - thr;
    if (b4 + 0 < NBUCK) { lsc[b4 + 0] = ex;                lb[b4 + 0] = a0 ? atomicAdd(&bcursor[b4 + 0], a0) : 0; }
    if (b4 + 1 < NBUCK) { lsc[b4 + 1] = ex + a0;           lb[b4 + 1] = a1 ? atomicAdd(&bcursor[b4 + 1], a1) : 0; }
    if (b4 + 2 < NBUCK) { lsc[b4 + 2] = ex + a0 + a1;      lb[b4 + 2] = a2 ? atomicAdd(&bcursor[b4 + 2], a2) : 0; }
    if (b4 + 3 < NBUCK) { lsc[b4 + 3] = ex + a0 + a1 + a2; lb[b4 + 3] = a3 ? atomicAdd(&bcursor[b4 + 3], a3) : 0; }
    __syncthreads();
    #pragma unroll
    for (int k = 0; k < EPT; ++k) {
        if (r[k] >= 0) {
            int bu = r[k] >> BUCK_SHIFT;
            se[lsc[bu] + rk[k]] = make_uint2((unsigned)r[k], (unsigned)c[k]);
        }
    }
    __syncthreads();
    #pragma unroll
    for (int k = 0; k < EPT; ++k) {
        int idx = k * 256 + t;
        if (e0 + idx < N_EDGES) {
            uint2 u = se[idx];
            int bu = (int)(u.x >> BUCK_SHIFT);
            int pos = lb[bu] + (idx - lsc[bu]);
            if (pos < CAP)
                bins[(size_t)bu * CAP + pos] = ((u.x & (BROWS - 1)) << 17) | u.y;
        }
    }
}

// ---------------------------------------------------------------- CSR build per bucket
__global__ __launch_bounds__(256) void csr_build_kernel(
        const unsigned* __restrict__ bins, const int* __restrict__ bcnt,
        int* __restrict__ csr_col, uint2* __restrict__ rowinfo,
        float* __restrict__ dinv, const int* __restrict__ cl,
        int* __restrict__ ccnt) {
    __shared__ int lcnt[BROWS];
    __shared__ int gbeg[BROWS];
    __shared__ int sc[BROWS];
    int b = blockIdx.x, t = threadIdx.x;
    int n = min(bcnt[b], CAP);
    const unsigned* eb = bins + (size_t)b * CAP;
    if (t < BROWS) lcnt[t] = 0;
    __syncthreads();
    for (int i = t; i < n; i += 256) atomicAdd(&lcnt[eb[i] >> 17], 1);
    __syncthreads();
    int v = (t < BROWS) ? lcnt[t] : 0;
    if (t < BROWS) sc[t] = v;
    __syncthreads();
    for (int off = 1; off < BROWS; off <<= 1) {
        int a = (t >= off && t < BROWS) ? sc[t - off] : 0;
        __syncthreads();
        if (t < BROWS) sc[t] += a;
        __syncthreads();
    }
    if (t < BROWS) {
        int beg = b * CAP + sc[t] - v;
        gbeg[t] = beg;
        int grow = (b << BUCK_SHIFT) + t;
        if (grow < N_NODES) {
            rowinfo[grow] = make_uint2((unsigned)beg, (unsigned)v);
            dinv[grow] = rsqrtf((float)(v + 1));
            atomicAdd(&ccnt[cl[grow]], 1);
        }
        lcnt[t] = 0;        // reuse as per-row cursor
    }
    __syncthreads();
    for (int i = t; i < n; i += 256) {
        unsigned u = eb[i];
        int lrow = (int)(u >> 17);
        int pos = atomicAdd(&lcnt[lrow], 1);
        csr_col[gbeg[lrow] + pos] = (int)(u & 0x1FFFFu);
    }
}

// ---------------------------------------------------------------- prologue: z0 = fp16(dinv * (x @ W^T))
__global__ __launch_bounds__(256, 8) void prologue_kernel(
        const float4* __restrict__ x4, const float* __restrict__ W,
        const float* __restrict__ dinv, half_t* __restrict__ z0) {
    __shared__ float Ws[OUT_F * 65];
    int t = threadIdx.x;
    for (int i = t; i < OUT_F * IN_F; i += 256)
        Ws[(i >> 6) * 65 + (i & 63)] = W[i];
    __syncthreads();
    int idx = blockIdx.x * 256 + t;
    if (idx >= N_NODES * OUT_F) return;
    int node = idx / OUT_F;
    int o = idx - node * OUT_F;
    const float4* xr = x4 + node * 16;
    const float* wr = Ws + o * 65;
    float acc = 0.f;
    #pragma unroll
    for (int k4 = 0; k4 < 16; ++k4) {
        float4 v = xr[k4];
        acc += v.x * wr[k4 * 4 + 0] + v.y * wr[k4 * 4 + 1]
             + v.z * wr[k4 * 4 + 2] + v.w * wr[k4 * 4 + 3];
    }
    z0[idx] = (half_t)(acc * dinv[node]);
}

// ---------------------------------------------------------------- 40-dim fp16 pull hop, 16 nodes/block
// wave per node group (slot 0..5 x ql 0..9, half4/lane = 80 B row => 2 lines/edge).
// fp32 accumulate; rows staged in LDS, flushed as one contiguous 1280 B burst.
// Gather loop keeps a UNIFORM trip count — __shfl BEFORE the guard (per-lane
// loop bounds read exec-masked-off lanes: absmax 3.7e-2 in R8/R9).
// Resubmission of R11: abort was diagnosed as infra flake, not a kernel fault.
template<int FINAL>
__global__ __launch_bounds__(256, 8) void hop40_kernel(
        const half_t* __restrict__ zin, half_t* __restrict__ zout,
        const uint2* __restrict__ rowinfo, const int* __restrict__ csr_col,
        const float* __restrict__ dinv, const int* __restrict__ cl,
        float* __restrict__ xc) {
    __shared__ half4_t srow[160];         // 16 rows x 10 half4 = 1280 B
    int t = threadIdx.x;
    int w = t >> 6;
    int lane = t & 63;
    int slot = lane / 10;                 // 6 => lanes 60..63 idle (still shfl sources)
    int ql = lane - slot * 10;
    int slotj = (slot < 6) ? slot : 1000; // idle slots never pass the j<lim guard
    int nb = blockIdx.x << 4;
    #pragma unroll
    for (int i = 0; i < 4; ++i) {
        int node = nb + (w << 2) + i;
        uint2 ri = rowinfo[node];
        int beg = (int)ri.x;
        int end = beg + (int)ri.y;
        float4 acc = make_float4(0.f, 0.f, 0.f, 0.f);
        if (slot == 0) {                  // self-loop
            half4_t v = ((const half4_t*)(zin + (size_t)node * OUT_F))[ql];
            acc.x = (float)v.x; acc.y = (float)v.y; acc.z = (float)v.z; acc.w = (float)v.w;
        }
        for (int base = beg; base < end; base += 64) {
            int idx = base + lane;
            int cv = (idx < end) ? csr_col[idx] : 0;
            int lim = min(64, end - base);
            #pragma unroll
            for (int r = 0; r < 11; ++r) {
                int j = r * 6 + slotj;                // uniform trip count, all lanes
                int c = __shfl(cv, j & 63);           // shfl BEFORE guard
                if (j < lim) {
                    half4_t v = ((const half4_t*)(zin + (size_t)c * OUT_F))[ql];
                    acc.x += (float)v.x; acc.y += (float)v.y;
                    acc.z += (float)v.z; acc.w += (float)v.w;
                }
            }
        }
        // reduce 6 slots: fold +30, then +10 and +20
        float4 t1;
        t1.x = __shfl(acc.x, (lane + 30) & 63); t1.y = __shfl(acc.y, (lane + 30) & 63);
        t1.z = __shfl(acc.z, (lane + 30) & 63); t1.w = __shfl(acc.w, (lane + 30) & 63);
        if (lane < 30) { acc.x += t1.x; acc.y += t1.y; acc.z += t1.z; acc.w += t1.w; }
        float4 t2, t3;
        t2.x = __shfl(acc.x, (lane + 10) & 63); t2.y = __shfl(acc.y, (lane + 10) & 63);
        t2.z = __shfl(acc.z, (lane + 10) & 63); t2.w = __shfl(acc.w, (lane + 10) & 63);
        t3.x = __shfl(acc.x, (lane + 20) & 63); t3.y = __shfl(acc.y, (lane + 20) & 63);
        t3.z = __shfl(acc.z, (lane + 20) & 63); t3.w = __shfl(acc.w, (lane + 20) & 63);
        if (lane < 10) {
            acc.x += t2.x + t3.x; acc.y += t2.y + t3.y;
            acc.z += t2.z + t3.z; acc.w += t2.w + t3.w;
            float d = dinv[node];
            if (FINAL) {
                float* p = xc + cl[node] * OUT_F + ql * 4;
                atomicAdd(p + 0, acc.x * d); atomicAdd(p + 1, acc.y * d);
                atomicAdd(p + 2, acc.z * d); atomicAdd(p + 3, acc.w * d);
            } else {
                float s = d * d;
                half4_t o;
                o.x = (half_t)(acc.x * s); o.y = (half_t)(acc.y * s);
                o.z = (half_t)(acc.z * s); o.w = (half_t)(acc.w * s);
                srow[((w << 2) + i) * 10 + ql] = o;
            }
        }
    }
    if (!FINAL) {
        __syncthreads();
        if (t < 160) ((half4_t*)zout)[(size_t)blockIdx.x * 160 + t] = srow[t];
    }
}

// ---------------------------------------------------------------- epilogue: out[n] = xc[cl[n]]/cnt + b
__global__ void epilogue_kernel(const float4* __restrict__ xc4, const int* __restrict__ ccnt,
                                const float4* __restrict__ b4, const int* __restrict__ cl,
                                float4* __restrict__ out4) {
    int i = blockIdx.x * 256 + threadIdx.x;
    if (i >= N_NODES * (OUT_F / 4)) return;
    int node = i / 10;
    int q = i - node * 10;
    int c = cl[node];
    float inv = 1.0f / fmaxf((float)ccnt[c], 1.0f);
    float4 v = xc4[c * 10 + q];
    float4 bb = b4[q];
    v.x = v.x * inv + bb.x; v.y = v.y * inv + bb.y;
    v.z = v.z * inv + bb.z; v.w = v.w * inv + bb.w;
    out4[i] = v;
}

// ---------------------------------------------------------------- launch
extern "C" void kernel_launch(void* const* d_in, const int* in_sizes, int n_in,
                              void* d_out, int out_size, void* d_ws, size_t ws_size,
                              hipStream_t stream) {
    const float* x    = (const float*)d_in[0];
    const int*   rows = (const int*)d_in[1];
    const int*   cols = (const int*)d_in[1] + N_EDGES;
    const int*   cl   = (const int*)d_in[2];
    const float* W    = (const float*)d_in[4];
    const float* b    = (const float*)d_in[5];
    float* out = (float*)d_out;

    size_t off = 0;
    auto alloc = [&](size_t elems) -> void* {          // 256 B aligned
        void* p = (char*)d_ws + off * 4;
        off += (elems + 63) & ~(size_t)63;
        return p;
    };
    // zeroed region first (single memset): ccnt | xc_sum | bcursor
    int*   ccnt    = (int*)alloc(N_CLUSTERS);
    float* xc_sum  = (float*)alloc((size_t)N_CLUSTERS * OUT_F);
    int*   bcursor = (int*)alloc(NBUCK);
    size_t zero_elems = off;
    float* dinv      = (float*)alloc(N_NODES);
    uint2* rowinfo   = (uint2*)alloc((size_t)N_NODES * 2);
    int*   csr_col   = (int*)alloc((size_t)NBUCK * CAP);             // 8 MB
    unsigned* bins   = (unsigned*)alloc((size_t)NBUCK * CAP);        // 8 MB
    half_t* bufA     = (half_t*)alloc((size_t)N_NODES * OUT_F / 2);  // 8 MB fp16
    half_t* bufB     = (half_t*)alloc((size_t)N_NODES * OUT_F / 2);  // 8 MB fp16
    (void)ws_size; (void)in_sizes; (void)n_in; (void)out_size;

    hipMemsetAsync(d_ws, 0, zero_elems * 4, stream);

    const int TB = (N_EDGES + TILE_E - 1) / TILE_E;   // 391
    const int HB = N_NODES / 16;                      // 6250

    bin_scatter_kernel<<<TB, 256, 0, stream>>>(rows, cols, bcursor, bins);
    csr_build_kernel<<<NBUCK, 256, 0, stream>>>(bins, bcursor, csr_col, rowinfo,
                                                dinv, cl, ccnt);

    prologue_kernel<<<(N_NODES * OUT_F + 255) / 256, 256, 0, stream>>>(
        (const float4*)x, W, dinv, bufA);

    hop40_kernel<0><<<HB, 256, 0, stream>>>(bufA, bufB, rowinfo, csr_col, dinv, cl, xc_sum);
    hop40_kernel<0><<<HB, 256, 0, stream>>>(bufB, bufA, rowinfo, csr_col, dinv, cl, xc_sum);
    hop40_kernel<1><<<HB, 256, 0, stream>>>(bufA, (half_t*)nullptr, rowinfo, csr_col, dinv, cl, xc_sum);

    epilogue_kernel<<<(N_NODES * (OUT_F / 4) + 255) / 256, 256, 0, stream>>>(
        (const float4*)xc_sum, ccnt, (const float4*)b, cl, (float4*)out);
}